// Round 10
// baseline (402.393 us; speedup 1.0000x reference)
//
#include <hip/hip_runtime.h>
#include <hip/hip_bf16.h>

using bf16   = __bf16;
using bf16x4 = __attribute__((ext_vector_type(4))) __bf16;
using bf16x8 = __attribute__((ext_vector_type(8))) __bf16;
using f32x4  = __attribute__((ext_vector_type(4))) float;

#define B_TOT 2048
#define NTOK  98
#define CDIM  192
#define NHEAD 6
#define HDIM  32
#define NWIN  512
#define NN    (NTOK*NTOK)            /* 9604 */
#define QKV_ELEMS ((size_t)B_TOT*NHEAD*NTOK*HDIM)  /* 38535168 */
#define MROWS 200704
#define SCALE 0.17677669529663687f   /* 32^-0.5 */

#define MFMA(a,b,c) __builtin_amdgcn_mfma_f32_16x16x32_bf16((a),(b),(c),0,0,0)

// async global->LDS, 16B per lane; LDS dest is wave-uniform base (+lane*16 by HW)
#define GLD16(gp, lp) __builtin_amdgcn_global_load_lds(                        \
    (const __attribute__((address_space(1))) void*)(gp),                       \
    (__attribute__((address_space(3))) void*)(lp), 16, 0, 0)

// ---------------------------------------------------------------------------
// bias[h][i][j] = rpb_table[rel_pos_index[i*98+j]][h]
// ---------------------------------------------------------------------------
__global__ void build_bias(const float* __restrict__ table,
                           const int* __restrict__ rel,
                           float* __restrict__ bias) {
    int t = blockIdx.x * 256 + threadIdx.x;
    if (t < NN) {
        int idx = rel[t];
        #pragma unroll
        for (int h = 0; h < NHEAD; ++h)
            bias[h * NN + t] = table[idx * NHEAD + h];
    }
}

// ---------------------------------------------------------------------------
// f32 -> bf16 converter with T2 row-XOR swizzle baked into storage:
// dst[row][ (c ^ (row&7))*8 .. +8 ] = src[row][c*8 .. +8], c = 16B chunk 0..23.
// Swizzle key = GLOBAL flat row index (consumers read with (m0+arow)&7).
// ---------------------------------------------------------------------------
__global__ void conv_swz(const float* __restrict__ src, bf16* __restrict__ dst,
                         int nchunk) {
    int t = blockIdx.x * 256 + threadIdx.x;
    if (t < nchunk) {
        int row = t / 24, c = t % 24;
        const float* s = src + (size_t)row * CDIM + c * 8;
        bf16x8 o;
        #pragma unroll
        for (int e = 0; e < 8; ++e) o[e] = (bf16)s[e];
        *(bf16x8*)(dst + (size_t)row * CDIM + ((c ^ (row & 7)) << 3)) = o;
    }
}

// ---------------------------------------------------------------------------
// QKV GEMM v7 (unchanged from round 9): m97-style 2-phase, BM=64,
// global_load_lds staging, baked swizzle, one barrier per chunk.
// ---------------------------------------------------------------------------
__global__ __launch_bounds__(256) void qkv_gemm(
    const bf16* __restrict__ xb, const bf16* __restrict__ wb,
    const float* __restrict__ bvec,
    bf16* __restrict__ qdst, bf16* __restrict__ kdst, bf16* __restrict__ vdst)
{
    __shared__ char As[24576];
    __shared__ char Bs[2][24576];
    const int tid = threadIdx.x, lane = tid & 63, wv = tid >> 6;
    const int l15 = lane & 15, l16 = lane >> 4;
    const int m0 = blockIdx.x * 64;

    {
        const char* asrc = (const char*)xb + (size_t)m0 * 384;
        const char* bsrc = (const char*)wb;
        #pragma unroll
        for (int j = 0; j < 6; ++j) {
            const int ch = wv * 6 + j;
            GLD16(asrc + ch * 1024 + lane * 16, As + ch * 1024);
            GLD16(bsrc + ch * 1024 + lane * 16, Bs[0] + ch * 1024);
        }
    }
    __syncthreads();

    const int arow = wv * 16 + l15;
    bf16x8 af[6];
    #pragma unroll
    for (int ks = 0; ks < 6; ++ks)
        af[ks] = *(const bf16x8*)(As + arow * 384 + (((ks * 4 + l16) ^ (arow & 7)) << 4));

    const int grow   = m0 + arow;
    const int rowoff = (grow / NTOK) * 18816 + (grow % NTOK) * 32;

    const f32x4 z4 = {0.f, 0.f, 0.f, 0.f};

    #pragma unroll
    for (int nc = 0; nc < 9; ++nc) {
        if (nc < 8) {
            const char* bsrc = (const char*)wb + (size_t)(nc + 1) * 24576;
            #pragma unroll
            for (int j = 0; j < 6; ++j) {
                const int ch = wv * 6 + j;
                GLD16(bsrc + ch * 1024 + lane * 16, Bs[(nc + 1) & 1] + ch * 1024);
            }
        }

        f32x4 acc[4];
        #pragma unroll
        for (int ct = 0; ct < 4; ++ct) acc[ct] = z4;

        #pragma unroll
        for (int ks = 0; ks < 6; ++ks) {
            #pragma unroll
            for (int ct = 0; ct < 4; ++ct) {
                const int brow = ct * 16 + l15;
                bf16x8 bf = *(const bf16x8*)(Bs[nc & 1] + brow * 384
                                             + (((ks * 4 + l16) ^ (brow & 7)) << 4));
                acc[ct] = MFMA(bf, af[ks], acc[ct]);
            }
        }

        #pragma unroll
        for (int ct = 0; ct < 4; ++ct) {
            const int g0    = nc * 64 + ct * 16;
            const int which = g0 / CDIM;
            const int cm    = g0 % CDIM;
            const int h     = cm >> 5, hd0 = cm & 31;
            const float4 bvf = *(const float4*)(bvec + g0 + l16 * 4);
            bf16x4 s;
            #pragma unroll
            for (int r = 0; r < 4; ++r) {
                float v = acc[ct][r] + ((const float*)&bvf)[r];
                if (which == 0) v *= SCALE;
                s[r] = (bf16)v;
            }
            bf16* dp = (which == 0) ? qdst : (which == 1) ? kdst : vdst;
            *(bf16x4*)(dp + rowoff + h * 3136 + hd0 + l16 * 4) = s;
        }
        __syncthreads();
    }
}

// ---------------------------------------------------------------------------
// Fused attention v8: SWAPPED QK^T (T12 idea) -> each lane owns ONE q-row
// (i = it*16 + l15) with j in 4-consecutive runs (j = jt*16 + l16*4 + r).
// mask+bias combined at init via float2 vector loads (28 vs 56 scalar),
// softmax = in-lane reduce + 2 shuffles (vs 32), P written as 7x bf16x4.
// ---------------------------------------------------------------------------
__global__ __launch_bounds__(448) void attn_fused(
    const bf16* __restrict__ q, const bf16* __restrict__ k,
    const bf16* __restrict__ v,
    const float* __restrict__ mask, const float* __restrict__ bias,
    bf16* __restrict__ ao)
{
    __shared__ char lds[8192 + 28672 + 512];
    char* Vt = lds;           // 32 x 128 bf16, 256B rows, swizzled
    char* P  = lds + 8192;    // 112 x 128 bf16, 256B rows, swizzled
    float* invS = (float*)(lds + 8192 + 28672);   // 112 floats

    const int bid = blockIdx.x;
    const int bh  = (bid & 7) * 1536 + (bid >> 3);
    const int b = bh / NHEAD, h = bh % NHEAD;
    const int w = b & (NWIN - 1);
    const int tid = threadIdx.x, lane = tid & 63, it = tid >> 6;
    const int l15 = lane & 15, l16 = lane >> 4;

    // stage V^T into LDS (transpose; pads zeroed below)
    const size_t bho = (size_t)bh * 3136;
    if (tid < 392) {
        int n = tid >> 2, hd0 = (tid & 3) * 8;
        bf16x8 vv = *(const bf16x8*)(v + bho + n * 32 + hd0);
        #pragma unroll
        for (int e = 0; e < 8; ++e) {
            int hd = hd0 + e;
            *(bf16*)(Vt + hd * 256 + (((n >> 3) ^ (hd & 7)) << 4) + ((n & 7) << 1)) = vv[e];
        }
    }
    for (int f = tid; f < 32 * 30; f += 448) {
        int hd = f / 30, n = 98 + f % 30;
        *(bf16*)(Vt + hd * 256 + (((n >> 3) ^ (hd & 7)) << 4) + ((n & 7) << 1)) = (bf16)0.f;
    }
    {
        int zr = it * 16 + l15;
        int zc = 112 + l16 * 4;
        *(unsigned long long*)(P + zr * 256 + (((zc >> 3) ^ (zr & 7)) << 4) + ((zc & 7) << 1)) = 0ull;
    }

    const int i  = it * 16 + l15;          // this lane's q-row (96..111 are pad)
    const int iL = i > 97 ? 97 : i;

    // combined mask+bias into registers: mb[jt][e], j = jt*16 + l16*4 + e.
    // float2 loads (8B-aligned: i*98 even, j0 multiple of 4); clamped in-bounds,
    // garbage values land only on j>=98 which are -inf'd below.
    const float* mrow = mask + (size_t)w * NN;
    const float* brow = bias + (size_t)h * NN;
    f32x4 mb[7];
    #pragma unroll
    for (int jt = 0; jt < 7; ++jt) {
        int off = iL * NTOK + jt * 16 + l16 * 4;
        int o0 = off     > NN - 2 ? NN - 2 : off;
        int o1 = off + 2 > NN - 2 ? NN - 2 : off + 2;
        float2 m0 = *(const float2*)(mrow + o0);
        float2 m1 = *(const float2*)(mrow + o1);
        float2 b0 = *(const float2*)(brow + o0);
        float2 b1 = *(const float2*)(brow + o1);
        mb[jt][0] = m0.x + b0.x; mb[jt][1] = m0.y + b0.y;
        mb[jt][2] = m1.x + b1.x; mb[jt][3] = m1.y + b1.y;
    }

    // QK^T, operands SWAPPED: lane holds S[i = it*16+l15][j = jt*16+l16*4+r]
    const bf16* qsrc = q + bho;
    const bf16* ksrc = k + bho;
    const bf16x8 qf = *(const bf16x8*)(qsrc + iL * HDIM + l16 * 8);
    const f32x4 z4 = {0.f, 0.f, 0.f, 0.f};
    f32x4 acc[7];
    #pragma unroll
    for (int jt = 0; jt < 7; ++jt) {
        int kr = jt * 16 + l15; if (kr > 97) kr = 97;
        bf16x8 kf = *(const bf16x8*)(ksrc + kr * HDIM + l16 * 8);
        acc[jt] = MFMA(kf, qf, z4);
    }

    // add mask+bias, -inf the j>=98 tail (jt==6, l16*4+e >= 2)
    #pragma unroll
    for (int jt = 0; jt < 7; ++jt) {
        #pragma unroll
        for (int e = 0; e < 4; ++e) {
            float vv = acc[jt][e] + mb[jt][e];
            if (jt == 6 && (l16 * 4 + e) >= 2) vv = -__builtin_inff();
            acc[jt][e] = vv;
        }
    }

    // softmax over the lane's row: in-lane reduce + 2 shuffles (xor 16, 32)
    float mx = acc[0][0];
    #pragma unroll
    for (int jt = 0; jt < 7; ++jt)
        #pragma unroll
        for (int e = 0; e < 4; ++e) mx = fmaxf(mx, acc[jt][e]);
    mx = fmaxf(mx, __shfl_xor(mx, 16));
    mx = fmaxf(mx, __shfl_xor(mx, 32));
    float s = 0.f;
    #pragma unroll
    for (int jt = 0; jt < 7; ++jt)
        #pragma unroll
        for (int e = 0; e < 4; ++e) {
            float ev = __expf(acc[jt][e] - mx);
            acc[jt][e] = ev; s += ev;
        }
    s += __shfl_xor(s, 16);
    s += __shfl_xor(s, 32);
    if (l16 == 0) invS[i] = 1.f / s;   // deferred normalization

    // write unnormalized P: 7 x bf16x4 vector stores (4-consecutive j)
    #pragma unroll
    for (int jt = 0; jt < 7; ++jt) {
        bf16x4 pk;
        #pragma unroll
        for (int e = 0; e < 4; ++e) pk[e] = (bf16)acc[jt][e];
        const int j0 = jt * 16 + l16 * 4;
        *(bf16x4*)(P + i * 256 + (((j0 >> 3) ^ (i & 7)) << 4) + ((j0 & 7) << 1)) = pk;
    }
    __syncthreads();   // Vt staged by all waves; also orders P for PV

    // PV (operand-swapped): lane holds row = it*16+l15, cols hd = l16*4+r (+16)
    f32x4 o0 = z4, o1 = z4;
    const int prow = it * 16 + l15;
    #pragma unroll
    for (int ks = 0; ks < 4; ++ks) {
        int kchunk = ks * 4 + l16;
        bf16x8 pf = *(const bf16x8*)(P + prow * 256 + ((kchunk ^ (prow & 7)) << 4));
        bf16x8 v0 = *(const bf16x8*)(Vt + l15 * 256 + ((kchunk ^ (l15 & 7)) << 4));
        bf16x8 v1 = *(const bf16x8*)(Vt + (16 + l15) * 256 + ((kchunk ^ (l15 & 7)) << 4));
        o0 = MFMA(v0, pf, o0);
        o1 = MFMA(v1, pf, o1);
    }

    {
        int row = it * 16 + l15;
        if (row < NTOK) {
            float inv = invS[row];
            bf16* dst = ao + (size_t)b * NTOK * CDIM;
            bf16x4 s0, s1;
            #pragma unroll
            for (int r = 0; r < 4; ++r) {
                s0[r] = (bf16)(o0[r] * inv);
                s1[r] = (bf16)(o1[r] * inv);
            }
            // swizzled store keyed on GLOBAL flat row (b*98+row):
            const int swr = (b * NTOK + row) & 7;
            const int c0 = h * 4 + (l16 >> 1);
            const int c1 = c0 + 2;
            const int wi = (l16 & 1) << 2;
            *(bf16x4*)(dst + (size_t)row * CDIM + (((c0 ^ swr) << 3) | wi)) = s0;
            *(bf16x4*)(dst + (size_t)row * CDIM + (((c1 ^ swr) << 3) | wi)) = s1;
        }
    }
}

// ---------------------------------------------------------------------------
// Proj GEMM v7 (unchanged from round 9).
// ---------------------------------------------------------------------------
__global__ __launch_bounds__(256) void proj_gemm(
    const bf16* __restrict__ ao, const bf16* __restrict__ wb,
    const float* __restrict__ bvec, float* __restrict__ out)
{
    __shared__ char As[24576];
    __shared__ char Bs[2][24576];
    const int tid = threadIdx.x, lane = tid & 63, wv = tid >> 6;
    const int l15 = lane & 15, l16 = lane >> 4;
    const int m0 = blockIdx.x * 64;

    {
        const char* asrc = (const char*)ao + (size_t)m0 * 384;
        const char* bsrc = (const char*)wb;
        #pragma unroll
        for (int j = 0; j < 6; ++j) {
            const int ch = wv * 6 + j;
            GLD16(asrc + ch * 1024 + lane * 16, As + ch * 1024);
            GLD16(bsrc + ch * 1024 + lane * 16, Bs[0] + ch * 1024);
        }
    }
    __syncthreads();

    const int arow = wv * 16 + l15;
    bf16x8 af[6];
    #pragma unroll
    for (int ks = 0; ks < 6; ++ks)
        af[ks] = *(const bf16x8*)(As + arow * 384 + (((ks * 4 + l16) ^ (arow & 7)) << 4));

    const size_t orow = (size_t)(m0 + arow) * CDIM;
    const f32x4 z4 = {0.f, 0.f, 0.f, 0.f};

    #pragma unroll
    for (int nc = 0; nc < 3; ++nc) {
        if (nc < 2) {
            const char* bsrc = (const char*)wb + (size_t)(nc + 1) * 24576;
            #pragma unroll
            for (int j = 0; j < 6; ++j) {
                const int ch = wv * 6 + j;
                GLD16(bsrc + ch * 1024 + lane * 16, Bs[(nc + 1) & 1] + ch * 1024);
            }
        }

        f32x4 acc[4];
        #pragma unroll
        for (int ct = 0; ct < 4; ++ct) acc[ct] = z4;

        #pragma unroll
        for (int ks = 0; ks < 6; ++ks) {
            #pragma unroll
            for (int ct = 0; ct < 4; ++ct) {
                const int brow = ct * 16 + l15;
                bf16x8 bf = *(const bf16x8*)(Bs[nc & 1] + brow * 384
                                             + (((ks * 4 + l16) ^ (brow & 7)) << 4));
                acc[ct] = MFMA(bf, af[ks], acc[ct]);
            }
        }

        #pragma unroll
        for (int ct = 0; ct < 4; ++ct) {
            const int g0 = nc * 64 + ct * 16;
            const float4 bvf = *(const float4*)(bvec + g0 + l16 * 4);
            f32x4 s;
            #pragma unroll
            for (int r = 0; r < 4; ++r)
                s[r] = acc[ct][r] + ((const float*)&bvf)[r];
            *(f32x4*)(out + orow + g0 + l16 * 4) = s;
        }
        __syncthreads();
    }
}

// ---------------------------------------------------------------------------
extern "C" void kernel_launch(void* const* d_in, const int* in_sizes, int n_in,
                              void* d_out, int out_size, void* d_ws, size_t ws_size,
                              hipStream_t stream)
{
    (void)in_sizes; (void)n_in; (void)out_size; (void)ws_size;
    const float* x      = (const float*)d_in[0];
    const float* mask   = (const float*)d_in[1];
    const float* qkv_w  = (const float*)d_in[2];
    const float* qkv_b  = (const float*)d_in[3];
    const float* proj_w = (const float*)d_in[4];
    const float* proj_b = (const float*)d_in[5];
    const float* rpb    = (const float*)d_in[6];
    const int*   rel    = (const int*)d_in[7];
    float* out = (float*)d_out;

    char* ws = (char*)d_ws;
    bf16* qb = (bf16*)ws;
    bf16* kb = qb + QKV_ELEMS;
    bf16* vb = kb + QKV_ELEMS;
    size_t off = 3 * QKV_ELEMS * sizeof(bf16);
    float* bias = (float*)(ws + off);
    off += ((size_t)NHEAD * NN * 4 + 255) / 256 * 256;
    bf16* ao = (bf16*)(ws + off);
    // overlapped buffers (same ws footprint as before):
    bf16* qwb = ao;               // swizzled qkv_w; dead before attn writes ao
    bf16* pwb = qb;               // swizzled proj_w; written after attn (qb dead)
    bf16* xb  = (bf16*)d_out;     // swizzled bf16 x; dead before proj writes out

    build_bias<<<(NN + 255) / 256, 256, 0, stream>>>(rpb, rel, bias);
    conv_swz<<<(MROWS * 24 + 255) / 256, 256, 0, stream>>>(x, xb, MROWS * 24);
    conv_swz<<<(576 * 24 + 255) / 256, 256, 0, stream>>>(qkv_w, qwb, 576 * 24);
    qkv_gemm<<<MROWS / 64, 256, 0, stream>>>(xb, qwb, qkv_b, qb, kb, vb);
    attn_fused<<<B_TOT * NHEAD, 448, 0, stream>>>(qb, kb, vb, mask, bias, ao);
    conv_swz<<<(192 * 24 + 255) / 256, 256, 0, stream>>>(proj_w, pwb, 192 * 24);
    proj_gemm<<<MROWS / 64, 256, 0, stream>>>(ao, pwb, proj_b, out);
}

// Round 11
// 342.728 us; speedup vs baseline: 1.1741x; 1.1741x over previous
//
#include <hip/hip_runtime.h>
#include <hip/hip_bf16.h>

using bf16   = __bf16;
using bf16x4 = __attribute__((ext_vector_type(4))) __bf16;
using bf16x8 = __attribute__((ext_vector_type(8))) __bf16;
using f32x4  = __attribute__((ext_vector_type(4))) float;

#define B_TOT 2048
#define NTOK  98
#define CDIM  192
#define NHEAD 6
#define HDIM  32
#define NWIN  512
#define NN    (NTOK*NTOK)            /* 9604 */
#define QKV_ELEMS ((size_t)B_TOT*NHEAD*NTOK*HDIM)  /* 38535168 */
#define MROWS 200704
#define SCALE 0.17677669529663687f   /* 32^-0.5 */

#define MFMA(a,b,c) __builtin_amdgcn_mfma_f32_16x16x32_bf16((a),(b),(c),0,0,0)

// async global->LDS, 16B per lane; LDS dest is wave-uniform base (+lane*16 by HW)
#define GLD16(gp, lp) __builtin_amdgcn_global_load_lds(                        \
    (const __attribute__((address_space(1))) void*)(gp),                       \
    (__attribute__((address_space(3))) void*)(lp), 16, 0, 0)

// ---------------------------------------------------------------------------
// bias[h][i][j] = rpb_table[rel_pos_index[i*98+j]][h]
// ---------------------------------------------------------------------------
__global__ void build_bias(const float* __restrict__ table,
                           const int* __restrict__ rel,
                           float* __restrict__ bias) {
    int t = blockIdx.x * 256 + threadIdx.x;
    if (t < NN) {
        int idx = rel[t];
        #pragma unroll
        for (int h = 0; h < NHEAD; ++h)
            bias[h * NN + t] = table[idx * NHEAD + h];
    }
}

// ---------------------------------------------------------------------------
// f32 -> bf16 weight converter with T2 row-XOR swizzle baked into storage
// (rows of length CDIM only — used for qkv_w and proj_w).
// ---------------------------------------------------------------------------
__global__ void conv_swz(const float* __restrict__ src, bf16* __restrict__ dst,
                         int nchunk) {
    int t = blockIdx.x * 256 + threadIdx.x;
    if (t < nchunk) {
        int row = t / 24, c = t % 24;
        const float* s = src + (size_t)row * CDIM + c * 8;
        bf16x8 o;
        #pragma unroll
        for (int e = 0; e < 8; ++e) o[e] = (bf16)s[e];
        *(bf16x8*)(dst + (size_t)row * CDIM + ((c ^ (row & 7)) << 3)) = o;
    }
}

// ---------------------------------------------------------------------------
// QKV GEMM v8: A-fragments loaded DIRECTLY from f32 x into registers
// (wave-private rows, once per block — kills the conv_swz(x) pass).
// B double-buffered in LDS via global_load_lds (one barrier per chunk).
// LDS 48KB -> 3 blocks/CU.
// ---------------------------------------------------------------------------
__global__ __launch_bounds__(256) void qkv_gemm(
    const float* __restrict__ x, const bf16* __restrict__ wb,
    const float* __restrict__ bvec,
    bf16* __restrict__ qdst, bf16* __restrict__ kdst, bf16* __restrict__ vdst)
{
    __shared__ char Bs[2][24576];
    const int tid = threadIdx.x, lane = tid & 63, wv = tid >> 6;
    const int l15 = lane & 15, l16 = lane >> 4;
    const int m0 = blockIdx.x * 64;

    // stage B chunk 0 (each wave moves 6 x 1KB)
    {
        const char* bsrc = (const char*)wb;
        #pragma unroll
        for (int j = 0; j < 6; ++j) {
            const int ch = wv * 6 + j;
            GLD16(bsrc + ch * 1024 + lane * 16, Bs[0] + ch * 1024);
        }
    }

    // A fragments straight from global f32 (row = wave-private)
    const int arow = wv * 16 + l15;
    const int grow = m0 + arow;
    const float* xr = x + (size_t)grow * CDIM + l16 * 8;
    bf16x8 af[6];
    #pragma unroll
    for (int ks = 0; ks < 6; ++ks) {
        float4 v0 = *(const float4*)(xr + ks * 32);
        float4 v1 = *(const float4*)(xr + ks * 32 + 4);
        bf16x8 a;
        a[0] = (bf16)v0.x; a[1] = (bf16)v0.y; a[2] = (bf16)v0.z; a[3] = (bf16)v0.w;
        a[4] = (bf16)v1.x; a[5] = (bf16)v1.y; a[6] = (bf16)v1.z; a[7] = (bf16)v1.w;
        af[ks] = a;
    }

    __syncthreads();   // drains vmcnt: B0 resident

    const int rowoff = (grow / NTOK) * 18816 + (grow % NTOK) * 32;
    const f32x4 z4 = {0.f, 0.f, 0.f, 0.f};

    #pragma unroll
    for (int nc = 0; nc < 9; ++nc) {
        if (nc < 8) {   // async-stage next B chunk before compute
            const char* bsrc = (const char*)wb + (size_t)(nc + 1) * 24576;
            #pragma unroll
            for (int j = 0; j < 6; ++j) {
                const int ch = wv * 6 + j;
                GLD16(bsrc + ch * 1024 + lane * 16, Bs[(nc + 1) & 1] + ch * 1024);
            }
        }

        f32x4 acc[4];
        #pragma unroll
        for (int ct = 0; ct < 4; ++ct) acc[ct] = z4;

        #pragma unroll
        for (int ks = 0; ks < 6; ++ks) {
            #pragma unroll
            for (int ct = 0; ct < 4; ++ct) {
                const int brow = ct * 16 + l15;
                bf16x8 bf = *(const bf16x8*)(Bs[nc & 1] + brow * 384
                                             + (((ks * 4 + l16) ^ (brow & 7)) << 4));
                acc[ct] = MFMA(bf, af[ks], acc[ct]);
            }
        }

        // epilogue for chunk nc: lane holds row = grow, cols g0 + l16*4 + r
        #pragma unroll
        for (int ct = 0; ct < 4; ++ct) {
            const int g0    = nc * 64 + ct * 16;   // compile-time
            const int which = g0 / CDIM;
            const int cm    = g0 % CDIM;
            const int h     = cm >> 5, hd0 = cm & 31;
            const float4 bvf = *(const float4*)(bvec + g0 + l16 * 4);
            bf16x4 s;
            #pragma unroll
            for (int r = 0; r < 4; ++r) {
                float v = acc[ct][r] + ((const float*)&bvf)[r];
                if (which == 0) v *= SCALE;
                s[r] = (bf16)v;
            }
            bf16* dp = (which == 0) ? qdst : (which == 1) ? kdst : vdst;
            *(bf16x4*)(dp + rowoff + h * 3136 + hd0 + l16 * 4) = s;
        }
        __syncthreads();   // B(nc+1) resident; reads of Bs[nc&1] complete
    }
}

// ---------------------------------------------------------------------------
// Fused attention (r9 version, reverted): one block per (window, head),
// 7 waves, one barrier, deferred softmax norm, XCD-chunked swizzle,
// ao stored with row-XOR chunk swizzle keyed on GLOBAL flat row.
// ---------------------------------------------------------------------------
__global__ __launch_bounds__(448) void attn_fused(
    const bf16* __restrict__ q, const bf16* __restrict__ k,
    const bf16* __restrict__ v,
    const float* __restrict__ mask, const float* __restrict__ bias,
    bf16* __restrict__ ao)
{
    __shared__ char lds[8192 + 28672 + 512];
    char* Vt = lds;           // 32 x 128 bf16, 256B rows, swizzled
    char* P  = lds + 8192;    // 112 x 128 bf16, 256B rows, swizzled
    float* invS = (float*)(lds + 8192 + 28672);   // 112 floats

    const int bid = blockIdx.x;
    const int bh  = (bid & 7) * 1536 + (bid >> 3);
    const int b = bh / NHEAD, h = bh % NHEAD;
    const int w = b & (NWIN - 1);
    const int tid = threadIdx.x, lane = tid & 63, it = tid >> 6;
    const int l15 = lane & 15, l16 = lane >> 4;

    const size_t bho = (size_t)bh * 3136;
    if (tid < 392) {
        int n = tid >> 2, hd0 = (tid & 3) * 8;
        bf16x8 vv = *(const bf16x8*)(v + bho + n * 32 + hd0);
        #pragma unroll
        for (int e = 0; e < 8; ++e) {
            int hd = hd0 + e;
            *(bf16*)(Vt + hd * 256 + (((n >> 3) ^ (hd & 7)) << 4) + ((n & 7) << 1)) = vv[e];
        }
    }
    for (int f = tid; f < 32 * 30; f += 448) {
        int hd = f / 30, n = 98 + f % 30;
        *(bf16*)(Vt + hd * 256 + (((n >> 3) ^ (hd & 7)) << 4) + ((n & 7) << 1)) = (bf16)0.f;
    }
    {
        int zr = it * 16 + l15;
        int zc = 112 + l16 * 4;
        *(unsigned long long*)(P + zr * 256 + (((zc >> 3) ^ (zr & 7)) << 4) + ((zc & 7) << 1)) = 0ull;
    }

    int qrow = it * 16 + l15; if (qrow > 97) qrow = 97;
    const bf16* qsrc = q + bho;
    const bf16* ksrc = k + bho;
    const bf16x8 qf = *(const bf16x8*)(qsrc + qrow * HDIM + l16 * 8);
    const f32x4 z4 = {0.f, 0.f, 0.f, 0.f};
    f32x4 acc[7];
    #pragma unroll
    for (int jt = 0; jt < 7; ++jt) {
        int kr = jt * 16 + l15; if (kr > 97) kr = 97;
        bf16x8 kf = *(const bf16x8*)(ksrc + kr * HDIM + l16 * 8);
        acc[jt] = MFMA(qf, kf, z4);
    }

    const float* mrow = mask + (size_t)w * NN;
    const float* brow = bias + (size_t)h * NN;
    #pragma unroll
    for (int r = 0; r < 4; ++r) {
        const int iact = it * 16 + l16 * 4 + r;
        int i = iact > 97 ? 97 : iact;
        #pragma unroll
        for (int jt = 0; jt < 7; ++jt) {
            int j = jt * 16 + l15;
            acc[jt][r] = (j < NTOK)
                ? (acc[jt][r] + mrow[i * NTOK + j] + brow[i * NTOK + j])
                : -__builtin_inff();
        }
        float m = acc[0][r];
        #pragma unroll
        for (int jt = 1; jt < 7; ++jt) m = fmaxf(m, acc[jt][r]);
        m = fmaxf(m, __shfl_xor(m, 1, 16));
        m = fmaxf(m, __shfl_xor(m, 2, 16));
        m = fmaxf(m, __shfl_xor(m, 4, 16));
        m = fmaxf(m, __shfl_xor(m, 8, 16));
        float s = 0.f;
        #pragma unroll
        for (int jt = 0; jt < 7; ++jt) {
            float e = __expf(acc[jt][r] - m);
            acc[jt][r] = e; s += e;
        }
        s += __shfl_xor(s, 1, 16);
        s += __shfl_xor(s, 2, 16);
        s += __shfl_xor(s, 4, 16);
        s += __shfl_xor(s, 8, 16);
        if (l15 == 0) invS[iact] = 1.f / s;
    }

    #pragma unroll
    for (int jt = 0; jt < 7; ++jt) {
        #pragma unroll
        for (int r = 0; r < 4; ++r) {
            int row = it * 16 + l16 * 4 + r;
            int j = jt * 16 + l15;
            *(bf16*)(P + row * 256 + (((j >> 3) ^ (row & 7)) << 4) + ((j & 7) << 1))
                = (bf16)acc[jt][r];
        }
    }
    __syncthreads();

    f32x4 o0 = z4, o1 = z4;
    const int prow = it * 16 + l15;
    #pragma unroll
    for (int ks = 0; ks < 4; ++ks) {
        int kchunk = ks * 4 + l16;
        bf16x8 pf = *(const bf16x8*)(P + prow * 256 + ((kchunk ^ (prow & 7)) << 4));
        bf16x8 v0 = *(const bf16x8*)(Vt + l15 * 256 + ((kchunk ^ (l15 & 7)) << 4));
        bf16x8 v1 = *(const bf16x8*)(Vt + (16 + l15) * 256 + ((kchunk ^ (l15 & 7)) << 4));
        o0 = MFMA(v0, pf, o0);
        o1 = MFMA(v1, pf, o1);
    }

    {
        int row = it * 16 + l15;
        if (row < NTOK) {
            float inv = invS[row];
            bf16* dst = ao + (size_t)b * NTOK * CDIM;
            bf16x4 s0, s1;
            #pragma unroll
            for (int r = 0; r < 4; ++r) {
                s0[r] = (bf16)(o0[r] * inv);
                s1[r] = (bf16)(o1[r] * inv);
            }
            // swizzled store keyed on GLOBAL flat row (b*98+row):
            const int swr = (b * NTOK + row) & 7;
            const int c0 = h * 4 + (l16 >> 1);
            const int c1 = c0 + 2;
            const int wi = (l16 & 1) << 2;
            *(bf16x4*)(dst + (size_t)row * CDIM + (((c0 ^ swr) << 3) | wi)) = s0;
            *(bf16x4*)(dst + (size_t)row * CDIM + (((c1 ^ swr) << 3) | wi)) = s1;
        }
    }
}

// ---------------------------------------------------------------------------
// Proj GEMM v7 (unchanged from round 9).
// ---------------------------------------------------------------------------
__global__ __launch_bounds__(256) void proj_gemm(
    const bf16* __restrict__ ao, const bf16* __restrict__ wb,
    const float* __restrict__ bvec, float* __restrict__ out)
{
    __shared__ char As[24576];
    __shared__ char Bs[2][24576];
    const int tid = threadIdx.x, lane = tid & 63, wv = tid >> 6;
    const int l15 = lane & 15, l16 = lane >> 4;
    const int m0 = blockIdx.x * 64;

    {
        const char* asrc = (const char*)ao + (size_t)m0 * 384;
        const char* bsrc = (const char*)wb;
        #pragma unroll
        for (int j = 0; j < 6; ++j) {
            const int ch = wv * 6 + j;
            GLD16(asrc + ch * 1024 + lane * 16, As + ch * 1024);
            GLD16(bsrc + ch * 1024 + lane * 16, Bs[0] + ch * 1024);
        }
    }
    __syncthreads();

    const int arow = wv * 16 + l15;
    bf16x8 af[6];
    #pragma unroll
    for (int ks = 0; ks < 6; ++ks)
        af[ks] = *(const bf16x8*)(As + arow * 384 + (((ks * 4 + l16) ^ (arow & 7)) << 4));

    const size_t orow = (size_t)(m0 + arow) * CDIM;
    const f32x4 z4 = {0.f, 0.f, 0.f, 0.f};

    #pragma unroll
    for (int nc = 0; nc < 3; ++nc) {
        if (nc < 2) {
            const char* bsrc = (const char*)wb + (size_t)(nc + 1) * 24576;
            #pragma unroll
            for (int j = 0; j < 6; ++j) {
                const int ch = wv * 6 + j;
                GLD16(bsrc + ch * 1024 + lane * 16, Bs[(nc + 1) & 1] + ch * 1024);
            }
        }

        f32x4 acc[4];
        #pragma unroll
        for (int ct = 0; ct < 4; ++ct) acc[ct] = z4;

        #pragma unroll
        for (int ks = 0; ks < 6; ++ks) {
            #pragma unroll
            for (int ct = 0; ct < 4; ++ct) {
                const int brow = ct * 16 + l15;
                bf16x8 bf = *(const bf16x8*)(Bs[nc & 1] + brow * 384
                                             + (((ks * 4 + l16) ^ (brow & 7)) << 4));
                acc[ct] = MFMA(bf, af[ks], acc[ct]);
            }
        }

        #pragma unroll
        for (int ct = 0; ct < 4; ++ct) {
            const int g0 = nc * 64 + ct * 16;
            const float4 bvf = *(const float4*)(bvec + g0 + l16 * 4);
            f32x4 s;
            #pragma unroll
            for (int r = 0; r < 4; ++r)
                s[r] = acc[ct][r] + ((const float*)&bvf)[r];
            *(f32x4*)(out + orow + g0 + l16 * 4) = s;
        }
        __syncthreads();
    }
}

// ---------------------------------------------------------------------------
extern "C" void kernel_launch(void* const* d_in, const int* in_sizes, int n_in,
                              void* d_out, int out_size, void* d_ws, size_t ws_size,
                              hipStream_t stream)
{
    (void)in_sizes; (void)n_in; (void)out_size; (void)ws_size;
    const float* x      = (const float*)d_in[0];
    const float* mask   = (const float*)d_in[1];
    const float* qkv_w  = (const float*)d_in[2];
    const float* qkv_b  = (const float*)d_in[3];
    const float* proj_w = (const float*)d_in[4];
    const float* proj_b = (const float*)d_in[5];
    const float* rpb    = (const float*)d_in[6];
    const int*   rel    = (const int*)d_in[7];
    float* out = (float*)d_out;

    char* ws = (char*)d_ws;
    bf16* qb = (bf16*)ws;
    bf16* kb = qb + QKV_ELEMS;
    bf16* vb = kb + QKV_ELEMS;
    size_t off = 3 * QKV_ELEMS * sizeof(bf16);
    float* bias = (float*)(ws + off);
    off += ((size_t)NHEAD * NN * 4 + 255) / 256 * 256;
    bf16* ao = (bf16*)(ws + off);
    // overlapped weight buffers:
    bf16* qwb = ao;               // swizzled qkv_w; dead before attn writes ao
    bf16* pwb = qb;               // swizzled proj_w; written after attn (qb dead)

    build_bias<<<(NN + 255) / 256, 256, 0, stream>>>(rpb, rel, bias);
    conv_swz<<<(576 * 24 + 255) / 256, 256, 0, stream>>>(qkv_w, qwb, 576 * 24);
    qkv_gemm<<<MROWS / 64, 256, 0, stream>>>(x, qwb, qkv_b, qb, kb, vb);
    attn_fused<<<B_TOT * NHEAD, 448, 0, stream>>>(qb, kb, vb, mask, bias, ao);
    conv_swz<<<(192 * 24 + 255) / 256, 256, 0, stream>>>(proj_w, pwb, 192 * 24);
    proj_gemm<<<MROWS / 64, 256, 0, stream>>>(ao, pwb, proj_b, out);
}